// Round 4
// baseline (1612.327 us; speedup 1.0000x reference)
//
#include <hip/hip_runtime.h>
#include <cstdint>

typedef unsigned short ushort_t;
typedef _Float16 half_t;
typedef __attribute__((ext_vector_type(8))) short short8;
typedef __attribute__((ext_vector_type(8))) half_t half8;
typedef __attribute__((ext_vector_type(4))) half_t half4;
typedef __attribute__((ext_vector_type(4))) float f32x4;

// ---------------- helpers ----------------
__device__ __forceinline__ void gld_lds16(const ushort_t* g, ushort_t* l) {
    __builtin_amdgcn_global_load_lds((const __attribute__((address_space(1))) void*)g,
                                     (__attribute__((address_space(3))) void*)l,
                                     16, 0, 0);
}

// ---------------- expand: X fp32 [N][IN] -> E fp16 [N][9][IN] ----------------
// plane c=0 is silu(x); planes c=1..8 are the 8 cubic B-spline bases (uniform grid).
template<int IN>
__global__ void expand_kernel(const float* __restrict__ X, half_t* __restrict__ E, int nrows) {
    int idx = blockIdx.x * 256 + threadIdx.x;
    if (idx >= nrows * IN) return;
    int n = idx / IN, i = idx % IN;
    float x = X[idx];
    float si = x / (1.0f + __expf(-x));
    float u = (x + 2.2f) * 2.5f;
    int ji = (int)floorf(u);
    float f = u - (float)ji;
    if (!(ji >= 0 && ji <= 10)) ji = -100;      // outside knot range -> all bases 0
    float f2 = f * f, f3 = f2 * f;
    float w_i   = f3 * (1.0f / 6.0f);                                   // N_{ji}
    float w_im1 = (1.0f + 3.0f * f + 3.0f * f2 - 3.0f * f3) * (1.0f/6.0f);
    float w_im2 = (4.0f - 6.0f * f2 + 3.0f * f3) * (1.0f/6.0f);
    float omf = 1.0f - f;
    float w_im3 = omf * omf * omf * (1.0f / 6.0f);                      // N_{ji-3}
    half_t* Er = E + (long)n * 9 * IN + i;
    Er[0] = (half_t)si;
    #pragma unroll
    for (int c = 0; c < 8; ++c) {
        float v = 0.0f;
        v = (c == ji    ) ? w_i   : v;
        v = (c == ji - 1) ? w_im1 : v;
        v = (c == ji - 2) ? w_im2 : v;
        v = (c == ji - 3) ? w_im3 : v;
        Er[(long)(c + 1) * IN] = (half_t)v;
    }
}

// ---------------- pack weights hi/lo: base[o][i], spline[o][i][8] -> Whi/Wlo fp16 [o][9][IN] ----------------
template<int IN>
__global__ void pack_kernel(const float* __restrict__ base, const float* __restrict__ spline,
                            half_t* __restrict__ Whi, half_t* __restrict__ Wlo, int nout) {
    int idx = blockIdx.x * 256 + threadIdx.x;
    if (idx >= nout * IN) return;
    int o = idx / IN, i = idx % IN;
    long r0 = (long)o * 9 * IN + i;
    float w[9];
    w[0] = base[idx];
    const f32x4* sp = (const f32x4*)(spline + (long)idx * 8);
    f32x4 s0 = sp[0], s1 = sp[1];
    w[1] = s0[0]; w[2] = s0[1]; w[3] = s0[2]; w[4] = s0[3];
    w[5] = s1[0]; w[6] = s1[1]; w[7] = s1[2]; w[8] = s1[3];
    #pragma unroll
    for (int c = 0; c < 9; ++c) {
        half_t hi = (half_t)w[c];
        half_t lo = (half_t)(w[c] - (float)hi);
        Whi[r0 + (long)c * IN] = hi;
        Wlo[r0 + (long)c * IN] = lo;
    }
}

// ---------------- GEMM: C[M][N] = A[M][K] @ B[N][K]^T, fp16 in / fp32 acc ----------------
// m97 structure: 128x128 tile, BK=64, 4 waves (2x2), 4x4 16x16x32 fragments/wave.
// NPASS=2: second K-sweep over Blo accumulating into the same acc (hi/lo weight split).
enum { EPI_RELU = 0, // relu -> fp32 to Cf [row*N+col]
       EPI_F32  = 1, // fp32 to Cf [row*N+col]
       EPI_S    = 2, // fp32*scale to Cf [z*sC + row*N + col]
       EPI_QKV  = 3, // 3-way fp16 scatter to Q/K/V [b,h,s,d]
       EPI_PV   = 4 };// fp32 head-merge scatter to Cf [(b*1024+s)*512 + h*128+d]

template<int EPI, int NPASS>
__global__ void gemm_bt(const ushort_t* __restrict__ A, const ushort_t* __restrict__ B,
                        const ushort_t* __restrict__ Blo, float* __restrict__ Cf,
                        half_t* __restrict__ Qp, half_t* __restrict__ Kp, half_t* __restrict__ Vp,
                        int M, int N, int K, long sA, long sB, long sC, float scale, int zoff) {
    __shared__ ushort_t As[128 * 64];
    __shared__ ushort_t Bs[128 * 64];
    const int tid = threadIdx.x;
    const int lane = tid & 63;
    const int wave = tid >> 6;
    const int wm = wave >> 1, wn = wave & 1;
    const int bm = blockIdx.x * 128, bn = blockIdx.y * 128;
    const int z = blockIdx.z;
    const ushort_t* Ab = A + (long)z * sA;
    const int l15 = lane & 15, l16 = lane >> 4;

    f32x4 acc[4][4];
    #pragma unroll
    for (int m = 0; m < 4; ++m)
        #pragma unroll
        for (int n = 0; n < 4; ++n) acc[m][n] = (f32x4){0.f, 0.f, 0.f, 0.f};

    #pragma unroll
    for (int pass = 0; pass < NPASS; ++pass) {
        const ushort_t* Bb = ((pass == 0) ? B : Blo) + (long)z * sB;
        for (int kt = 0; kt < K; kt += 64) {
            #pragma unroll
            for (int r = 0; r < 4; ++r) {
                int chunk = r * 256 + tid;          // 1024 chunks of 8 fp16 per tile
                int row = chunk >> 3;
                int col = (chunk & 7) << 3;
                gld_lds16(Ab + (long)(bm + row) * K + kt + col, &As[chunk * 8]);
                gld_lds16(Bb + (long)(bn + row) * K + kt + col, &Bs[chunk * 8]);
            }
            __syncthreads();
            #pragma unroll
            for (int kk = 0; kk < 2; ++kk) {
                half8 af[4], bfr[4];
                #pragma unroll
                for (int m = 0; m < 4; ++m)
                    af[m] = __builtin_bit_cast(half8, *(const short8*)&As[(wm * 64 + m * 16 + l15) * 64 + kk * 32 + l16 * 8]);
                #pragma unroll
                for (int n = 0; n < 4; ++n)
                    bfr[n] = __builtin_bit_cast(half8, *(const short8*)&Bs[(wn * 64 + n * 16 + l15) * 64 + kk * 32 + l16 * 8]);
                #pragma unroll
                for (int m = 0; m < 4; ++m)
                    #pragma unroll
                    for (int n = 0; n < 4; ++n)
                        acc[m][n] = __builtin_amdgcn_mfma_f32_16x16x32_f16(af[m], bfr[n], acc[m][n], 0, 0, 0);
            }
            __syncthreads();
        }
    }

    // epilogue: C/D layout col=lane&15, row=(lane>>4)*4+j (m89-verified)
    #pragma unroll
    for (int m = 0; m < 4; ++m) {
        #pragma unroll
        for (int n = 0; n < 4; ++n) {
            #pragma unroll
            for (int j = 0; j < 4; ++j) {
                int row = bm + wm * 64 + m * 16 + l16 * 4 + j;
                int col = bn + wn * 64 + n * 16 + l15;
                float v = acc[m][n][j];
                if constexpr (EPI == EPI_RELU) {
                    Cf[(long)row * N + col] = fmaxf(v, 0.0f);
                } else if constexpr (EPI == EPI_F32) {
                    Cf[(long)row * N + col] = v;
                } else if constexpr (EPI == EPI_S) {
                    Cf[(long)z * sC + (long)row * N + col] = v * scale;
                } else if constexpr (EPI == EPI_QKV) {
                    // col in [0,1536): 0..511 Q, 512..1023 K, 1024..1535 V; layout [b,h,s,d]
                    int which = col >> 9, w5 = col & 511, h = w5 >> 7, d = w5 & 127;
                    int b = row >> 10, s = row & 1023;
                    half_t* dst = (which == 0) ? Qp : ((which == 1) ? Kp : Vp);
                    dst[(((long)(b * 4 + h) * 1024 + s) << 7) + d] = (half_t)v;
                } else if constexpr (EPI == EPI_PV) {
                    int bh = zoff + z;
                    int b = bh >> 2, h = bh & 3;
                    Cf[((long)(b * 1024 + row) * 512) + h * 128 + col] = v;
                }
            }
        }
    }
}

// ---------------- V transpose: [bh][s][d] -> [bh][d][s] (bit-pattern copy) ----------------
__global__ void transpose_v(const ushort_t* __restrict__ V, ushort_t* __restrict__ Vt) {
    __shared__ ushort_t t[64][72];
    int s0 = blockIdx.x * 64, d0 = blockIdx.y * 64, bh = blockIdx.z;
    const ushort_t* Vb = V + (long)bh * 1024 * 128;
    ushort_t* Vtb = Vt + (long)bh * 128 * 1024;
    int tid = threadIdx.x;
    int r = tid >> 2, g = tid & 3;
    #pragma unroll
    for (int j = 0; j < 16; ++j)
        t[r][g * 16 + j] = Vb[(long)(s0 + r) * 128 + d0 + g * 16 + j];
    __syncthreads();
    #pragma unroll
    for (int j = 0; j < 16; ++j)
        Vtb[(long)(d0 + r) * 1024 + s0 + g * 16 + j] = t[g * 16 + j][r];
}

// ---------------- softmax over rows of 1024, fp32 in -> fp16 out ----------------
__global__ void softmax_kernel(const float* __restrict__ S, half_t* __restrict__ P) {
    long row = (long)blockIdx.x * 4 + (threadIdx.x >> 6);
    int lane = threadIdx.x & 63;
    const float* Sr = S + row * 1024;
    f32x4 v[4];
    float mx = -3.0e38f;
    #pragma unroll
    for (int c = 0; c < 4; ++c) {
        v[c] = *(const f32x4*)&Sr[c * 256 + lane * 4];
        mx = fmaxf(mx, fmaxf(fmaxf(v[c][0], v[c][1]), fmaxf(v[c][2], v[c][3])));
    }
    #pragma unroll
    for (int off = 32; off > 0; off >>= 1) mx = fmaxf(mx, __shfl_xor(mx, off));
    float sum = 0.0f;
    #pragma unroll
    for (int c = 0; c < 4; ++c) {
        v[c][0] = __expf(v[c][0] - mx); v[c][1] = __expf(v[c][1] - mx);
        v[c][2] = __expf(v[c][2] - mx); v[c][3] = __expf(v[c][3] - mx);
        sum += v[c][0] + v[c][1] + v[c][2] + v[c][3];
    }
    #pragma unroll
    for (int off = 32; off > 0; off >>= 1) sum += __shfl_xor(sum, off);
    float inv = 1.0f / sum;
    half_t* Pr = P + row * 1024;
    #pragma unroll
    for (int c = 0; c < 4; ++c) {
        half4 o = { (half_t)(v[c][0] * inv), (half_t)(v[c][1] * inv),
                    (half_t)(v[c][2] * inv), (half_t)(v[c][3] * inv) };
        *(half4*)&Pr[c * 256 + lane * 4] = o;
    }
}

// ---------------- residual + LayerNorm over rows of 512 ----------------
__global__ void ln_kernel(const float* __restrict__ O, const float* __restrict__ X,
                          const float* __restrict__ g, const float* __restrict__ b,
                          float* __restrict__ out) {
    long row = (long)blockIdx.x * 4 + (threadIdx.x >> 6);
    int lane = threadIdx.x & 63;
    long base = row * 512 + lane * 8;
    f32x4 o0 = *(const f32x4*)&O[base], o1 = *(const f32x4*)&O[base + 4];
    f32x4 x0 = *(const f32x4*)&X[base], x1 = *(const f32x4*)&X[base + 4];
    float y[8];
    #pragma unroll
    for (int j = 0; j < 4; ++j) { y[j] = o0[j] + x0[j]; y[j + 4] = o1[j] + x1[j]; }
    float s = 0.f;
    #pragma unroll
    for (int j = 0; j < 8; ++j) s += y[j];
    #pragma unroll
    for (int off = 32; off > 0; off >>= 1) s += __shfl_xor(s, off);
    float mu = s * (1.0f / 512.0f);
    float vs = 0.f;
    #pragma unroll
    for (int j = 0; j < 8; ++j) { float d = y[j] - mu; vs += d * d; }
    #pragma unroll
    for (int off = 32; off > 0; off >>= 1) vs += __shfl_xor(vs, off);
    float r = rsqrtf(vs * (1.0f / 512.0f) + 1e-5f);
    f32x4 w0 = *(const f32x4*)&g[lane * 8], w1 = *(const f32x4*)&g[lane * 8 + 4];
    f32x4 b0 = *(const f32x4*)&b[lane * 8], b1 = *(const f32x4*)&b[lane * 8 + 4];
    f32x4 r0, r1;
    #pragma unroll
    for (int j = 0; j < 4; ++j) {
        r0[j] = (y[j] - mu) * r * w0[j] + b0[j];
        r1[j] = (y[j + 4] - mu) * r * w1[j] + b1[j];
    }
    *(f32x4*)&out[base] = r0;
    *(f32x4*)&out[base + 4] = r1;
}

// ---------------- launch ----------------
extern "C" void kernel_launch(void* const* d_in, const int* in_sizes, int n_in,
                              void* d_out, int out_size, void* d_ws, size_t ws_size,
                              hipStream_t stream) {
    const float* x         = (const float*)d_in[0];
    const float* k1_base   = (const float*)d_in[1];
    const float* k1_spline = (const float*)d_in[2];
    const float* k2_base   = (const float*)d_in[3];
    const float* k2_spline = (const float*)d_in[4];
    const float* q_base    = (const float*)d_in[5];
    const float* q_spline  = (const float*)d_in[6];
    const float* k_base    = (const float*)d_in[7];
    const float* k_spline  = (const float*)d_in[8];
    const float* v_base    = (const float*)d_in[9];
    const float* v_spline  = (const float*)d_in[10];
    const float* o_base    = (const float*)d_in[11];
    const float* o_spline  = (const float*)d_in[12];
    const float* ln_w      = (const float*)d_in[13];
    const float* ln_b      = (const float*)d_in[14];
    float* out = (float*)d_out;

    constexpr int Dm = 512, HD = 1024, NR = 8192;
    constexpr int K1 = 9 * Dm;   // 4608
    constexpr int K2 = 9 * HD;   // 9216
    constexpr long SQ = (long)1024 * 128;       // per-bh Q/K/V stride (elements)
    constexpr long SS = (long)1024 * 1024;      // per-bh score stride (elements)

    // ---- workspace map (~216 MB peak, sequential slot reuse; proven-safe < 236 MB) ----
    char* p = (char*)d_ws;
    size_t off = 0;
    auto take = [&](size_t bytes) -> char* {
        char* r = p + off;
        off += (bytes + 255) & ~(size_t)255;
        return r;
    };
    half_t* W1hi = (half_t*)take((size_t)HD * K1 * 2);        //  9 MB
    half_t* W2hi = (half_t*)take((size_t)Dm * K2 * 2);        //  9 MB
    half_t* Wqhi = (half_t*)take((size_t)3 * Dm * K1 * 2);    // 13.5 MB
    half_t* Wohi = (half_t*)take((size_t)Dm * K1 * 2);        //  4.5 MB
    half_t* W1lo = (half_t*)take((size_t)HD * K1 * 2);        //  9 MB
    half_t* W2lo = (half_t*)take((size_t)Dm * K2 * 2);        //  9 MB
    half_t* Wqlo = (half_t*)take((size_t)3 * Dm * K1 * 2);    // 13.5 MB
    half_t* Wolo = (half_t*)take((size_t)Dm * K1 * 2);        //  4.5 MB
    char*   BIG  = take((size_t)72 * 1024 * 1024);            // 72 MB: E (<=72) | Schk(32)+Pchk(16)
    char*   R1   = take((size_t)NR * HD * 4);                 // 32 MB: H1 fp32 -> Vt fp16 + AO fp32
    char*   R2   = take((size_t)3 * NR * Dm * 2);             // 24 MB: Q,K,V fp16 -> Ofp fp32
    char*   R3   = take((size_t)NR * Dm * 4);                 // 16 MB: H2 fp32
    (void)ws_size; (void)in_sizes; (void)n_in; (void)out_size;

    half_t*  E    = (half_t*)BIG;
    float*   Schk = (float*)BIG;                               // 8 bh * 1M fp32 = 32 MB
    half_t*  Pchk = (half_t*)(BIG + (size_t)8 * SS * 4);       // 16 MB
    float*   H1   = (float*)R1;
    half_t*  Vt   = (half_t*)R1;                               // 8 MB (after H1 dead)
    float*   AO   = (float*)(R1 + (size_t)8 * 1024 * 1024);    // 16 MB (after H1 dead)
    half_t*  Qb   = (half_t*)R2;
    half_t*  Kb   = Qb + (size_t)NR * Dm;
    half_t*  Vb   = Kb + (size_t)NR * Dm;
    float*   Ofp  = (float*)R2;                                // 16 MB (after QKV dead)
    float*   H2   = (float*)R3;

    // pack weights to fp16 hi/lo [out][9][in]
    pack_kernel<Dm><<<(HD * Dm) / 256, 256, 0, stream>>>(k1_base, k1_spline, W1hi, W1lo, HD);
    pack_kernel<HD><<<(Dm * HD) / 256, 256, 0, stream>>>(k2_base, k2_spline, W2hi, W2lo, Dm);
    pack_kernel<Dm><<<(Dm * Dm) / 256, 256, 0, stream>>>(q_base, q_spline, Wqhi, Wqlo, Dm);
    pack_kernel<Dm><<<(Dm * Dm) / 256, 256, 0, stream>>>(k_base, k_spline, Wqhi + (size_t)Dm * K1, Wqlo + (size_t)Dm * K1, Dm);
    pack_kernel<Dm><<<(Dm * Dm) / 256, 256, 0, stream>>>(v_base, v_spline, Wqhi + (size_t)2 * Dm * K1, Wqlo + (size_t)2 * Dm * K1, Dm);
    pack_kernel<Dm><<<(Dm * Dm) / 256, 256, 0, stream>>>(o_base, o_spline, Wohi, Wolo, Dm);

    // KAN1: E1 = expand(x); H1 = relu(E1 @ W1^T)  (fp32)
    expand_kernel<Dm><<<(NR * Dm) / 256, 256, 0, stream>>>(x, E, NR);
    gemm_bt<EPI_RELU, 2><<<dim3(NR / 128, HD / 128, 1), 256, 0, stream>>>(
        (const ushort_t*)E, (const ushort_t*)W1hi, (const ushort_t*)W1lo, H1,
        nullptr, nullptr, nullptr, NR, HD, K1, 0, 0, 0, 1.f, 0);

    // KAN2 (M-chunked x2, E-chunk 72 MB): H2 = E2 @ W2^T (fp32)
    for (int c = 0; c < 2; ++c) {
        const float* h1c = H1 + (size_t)c * 4096 * HD;
        float* h2c = H2 + (size_t)c * 4096 * Dm;
        expand_kernel<HD><<<(4096 * HD) / 256, 256, 0, stream>>>(h1c, E, 4096);
        gemm_bt<EPI_F32, 2><<<dim3(4096 / 128, Dm / 128, 1), 256, 0, stream>>>(
            (const ushort_t*)E, (const ushort_t*)W2hi, (const ushort_t*)W2lo, h2c,
            nullptr, nullptr, nullptr, 4096, Dm, K2, 0, 0, 0, 1.f, 0);
    }

    // QKV projections (fused): E3 = expand(H2); scatter to Q/K/V [b,h,s,d] fp16
    expand_kernel<Dm><<<(NR * Dm) / 256, 256, 0, stream>>>(H2, E, NR);
    gemm_bt<EPI_QKV, 2><<<dim3(NR / 128, (3 * Dm) / 128, 1), 256, 0, stream>>>(
        (const ushort_t*)E, (const ushort_t*)Wqhi, (const ushort_t*)Wqlo, nullptr,
        Qb, Kb, Vb, NR, 3 * Dm, K1, 0, 0, 0, 1.f, 0);

    // attention, 4 chunks of 8 bh: S = (Q K^T)/sqrt(128); P = softmax(S); AO = P V (fp32)
    transpose_v<<<dim3(16, 2, 32), 256, 0, stream>>>((const ushort_t*)Vb, (ushort_t*)Vt);
    for (int c = 0; c < 4; ++c) {
        int zoff = c * 8;
        gemm_bt<EPI_S, 1><<<dim3(8, 8, 8), 256, 0, stream>>>(
            (const ushort_t*)(Qb + (long)zoff * SQ), (const ushort_t*)(Kb + (long)zoff * SQ),
            nullptr, Schk, nullptr, nullptr, nullptr,
            1024, 1024, 128, SQ, SQ, SS, 0.08838834764831845f, 0);
        softmax_kernel<<<(8 * 1024) / 4, 256, 0, stream>>>(Schk, Pchk);
        gemm_bt<EPI_PV, 1><<<dim3(8, 1, 8), 256, 0, stream>>>(
            (const ushort_t*)Pchk, (const ushort_t*)(Vt + (long)zoff * SQ),
            nullptr, AO, nullptr, nullptr, nullptr,
            1024, 128, 1024, SS, SQ, 0, 1.f, zoff);
    }

    // output projection: E4 = expand(AO); Ofp = E4 @ Wo^T (fp32)
    expand_kernel<Dm><<<(NR * Dm) / 256, 256, 0, stream>>>(AO, E, NR);
    gemm_bt<EPI_F32, 2><<<dim3(NR / 128, Dm / 128, 1), 256, 0, stream>>>(
        (const ushort_t*)E, (const ushort_t*)Wohi, (const ushort_t*)Wolo, Ofp,
        nullptr, nullptr, nullptr, NR, Dm, K1, 0, 0, 0, 1.f, 0);

    // residual + LayerNorm
    ln_kernel<<<NR / 4, 256, 0, stream>>>(Ofp, x, ln_w, ln_b, out);
}

// Round 5
// 1196.644 us; speedup vs baseline: 1.3474x; 1.3474x over previous
//
#include <hip/hip_runtime.h>
#include <cstdint>

typedef unsigned short ushort_t;
typedef _Float16 half_t;
typedef __attribute__((ext_vector_type(8))) short short8;
typedef __attribute__((ext_vector_type(8))) half_t half8;
typedef __attribute__((ext_vector_type(4))) half_t half4;
typedef __attribute__((ext_vector_type(4))) float f32x4;

// ---------------- helpers ----------------
__device__ __forceinline__ void gld_lds16(const ushort_t* g, ushort_t* l) {
    __builtin_amdgcn_global_load_lds((const __attribute__((address_space(1))) void*)g,
                                     (__attribute__((address_space(3))) void*)l,
                                     16, 0, 0);
}

// ---------------- expand: X fp32 [N][IN] -> E fp16 [N][9][IN] ----------------
// plane c=0 is silu(x); planes c=1..8 are the 8 cubic B-spline bases (uniform grid).
template<int IN>
__global__ void expand_kernel(const float* __restrict__ X, half_t* __restrict__ E, int nrows) {
    int idx = blockIdx.x * 256 + threadIdx.x;
    if (idx >= nrows * IN) return;
    int n = idx / IN, i = idx % IN;
    float x = X[idx];
    float si = x / (1.0f + __expf(-x));
    float u = (x + 2.2f) * 2.5f;
    int ji = (int)floorf(u);
    float f = u - (float)ji;
    if (!(ji >= 0 && ji <= 10)) ji = -100;      // outside knot range -> all bases 0
    float f2 = f * f, f3 = f2 * f;
    float w_i   = f3 * (1.0f / 6.0f);                                   // N_{ji}
    float w_im1 = (1.0f + 3.0f * f + 3.0f * f2 - 3.0f * f3) * (1.0f/6.0f);
    float w_im2 = (4.0f - 6.0f * f2 + 3.0f * f3) * (1.0f/6.0f);
    float omf = 1.0f - f;
    float w_im3 = omf * omf * omf * (1.0f / 6.0f);                      // N_{ji-3}
    half_t* Er = E + (long)n * 9 * IN + i;
    Er[0] = (half_t)si;
    #pragma unroll
    for (int c = 0; c < 8; ++c) {
        float v = 0.0f;
        v = (c == ji    ) ? w_i   : v;
        v = (c == ji - 1) ? w_im1 : v;
        v = (c == ji - 2) ? w_im2 : v;
        v = (c == ji - 3) ? w_im3 : v;
        Er[(long)(c + 1) * IN] = (half_t)v;
    }
}

// ---------------- pack weights hi/lo: base[o][i], spline[o][i][8] -> Whi/Wlo fp16 [o][9][IN] ----------------
template<int IN>
__global__ void pack_kernel(const float* __restrict__ base, const float* __restrict__ spline,
                            half_t* __restrict__ Whi, half_t* __restrict__ Wlo, int nout) {
    int idx = blockIdx.x * 256 + threadIdx.x;
    if (idx >= nout * IN) return;
    int o = idx / IN, i = idx % IN;
    long r0 = (long)o * 9 * IN + i;
    float w[9];
    w[0] = base[idx];
    const f32x4* sp = (const f32x4*)(spline + (long)idx * 8);
    f32x4 s0 = sp[0], s1 = sp[1];
    w[1] = s0[0]; w[2] = s0[1]; w[3] = s0[2]; w[4] = s0[3];
    w[5] = s1[0]; w[6] = s1[1]; w[7] = s1[2]; w[8] = s1[3];
    #pragma unroll
    for (int c = 0; c < 9; ++c) {
        half_t hi = (half_t)w[c];
        half_t lo = (half_t)(w[c] - (float)hi);
        Whi[r0 + (long)c * IN] = hi;
        Wlo[r0 + (long)c * IN] = lo;
    }
}

// ---------------- GEMM: C[M][N] = A[M][K] @ B[N][K]^T, fp16 in / fp32 acc ----------------
// tile 128 x TN, BK=64, 4 waves (2x2). KSPLIT==1: serial hi(+lo) passes, direct epilogue,
// blockIdx.z = batch. KSPLIT>1: blockIdx.z = K-split slice over virtual 2K (hi then lo),
// writes fp32 partial P[z*M*N + row*N + col]; epilogue applied by reduce_kernel.
enum { EPI_PART = 0, EPI_QKV = 1, EPI_S = 2, EPI_PV = 3 };

template<int EPI, int TN, int NPASS, int KSPLIT>
__global__ void gemm_t(const ushort_t* __restrict__ A, const ushort_t* __restrict__ Bhi,
                       const ushort_t* __restrict__ Blo, float* __restrict__ Cf,
                       float* __restrict__ P,
                       half_t* __restrict__ Qp, half_t* __restrict__ Kp, half_t* __restrict__ Vp,
                       int M, int N, int K, long sA, long sB, long sC, float scale, int zoff) {
    constexpr int NF = TN / 32;                 // B-frags per wave (2 or 4)
    __shared__ ushort_t As[128 * 64];
    __shared__ ushort_t Bs[TN * 64];
    const int tid = threadIdx.x;
    const int lane = tid & 63;
    const int wave = tid >> 6;
    const int wm = wave >> 1, wn = wave & 1;
    const int bm = blockIdx.x * 128, bn = blockIdx.y * TN;
    const int z = blockIdx.z;
    const int l15 = lane & 15, l16 = lane >> 4;

    f32x4 acc[4][NF];
    #pragma unroll
    for (int m = 0; m < 4; ++m)
        #pragma unroll
        for (int n = 0; n < NF; ++n) acc[m][n] = (f32x4){0.f, 0.f, 0.f, 0.f};

    auto sweep = [&](const ushort_t* Ab, const ushort_t* Bb, int ka, int kb) {
        for (int kt = ka; kt < kb; kt += 64) {
            #pragma unroll
            for (int r = 0; r < 4; ++r) {
                int chunk = r * 256 + tid;      // A: 128x64 fp16 = 1024 chunks of 8
                gld_lds16(Ab + (long)(bm + (chunk >> 3)) * K + kt + ((chunk & 7) << 3), &As[chunk * 8]);
            }
            #pragma unroll
            for (int r = 0; r < NF; ++r) {
                int chunk = r * 256 + tid;      // B: TNx64
                gld_lds16(Bb + (long)(bn + (chunk >> 3)) * K + kt + ((chunk & 7) << 3), &Bs[chunk * 8]);
            }
            __syncthreads();
            #pragma unroll
            for (int kk = 0; kk < 2; ++kk) {
                half8 af[4], bfr[NF];
                #pragma unroll
                for (int m = 0; m < 4; ++m)
                    af[m] = __builtin_bit_cast(half8, *(const short8*)&As[(wm * 64 + m * 16 + l15) * 64 + kk * 32 + l16 * 8]);
                #pragma unroll
                for (int n = 0; n < NF; ++n)
                    bfr[n] = __builtin_bit_cast(half8, *(const short8*)&Bs[(wn * (TN / 2) + n * 16 + l15) * 64 + kk * 32 + l16 * 8]);
                #pragma unroll
                for (int m = 0; m < 4; ++m)
                    #pragma unroll
                    for (int n = 0; n < NF; ++n)
                        acc[m][n] = __builtin_amdgcn_mfma_f32_16x16x32_f16(af[m], bfr[n], acc[m][n], 0, 0, 0);
            }
            __syncthreads();
        }
    };

    if constexpr (KSPLIT > 1) {
        constexpr int half = KSPLIT / 2;
        const ushort_t* Bsel = (z >= half) ? Blo : Bhi;
        int kc = K / half;
        int ka = (z % half) * kc;
        sweep(A, Bsel, ka, ka + kc);
    } else {
        const ushort_t* Ab = A + (long)z * sA;
        sweep(Ab, Bhi + (long)z * sB, 0, K);
        if constexpr (NPASS == 2) sweep(Ab, Blo + (long)z * sB, 0, K);
    }

    // epilogue: C/D layout col=lane&15, row=(lane>>4)*4+j (m89-verified)
    #pragma unroll
    for (int m = 0; m < 4; ++m) {
        #pragma unroll
        for (int n = 0; n < NF; ++n) {
            #pragma unroll
            for (int j = 0; j < 4; ++j) {
                int row = bm + wm * 64 + m * 16 + l16 * 4 + j;
                int col = bn + wn * (TN / 2) + n * 16 + l15;
                float v = acc[m][n][j];
                if constexpr (KSPLIT > 1) {
                    P[(size_t)z * M * N + (long)row * N + col] = v;
                } else if constexpr (EPI == EPI_QKV) {
                    // col in [0,1536): 0..511 Q, 512..1023 K, 1024..1535 V; layout [b,h,s,d]
                    int which = col >> 9, w5 = col & 511, h = w5 >> 7, d = w5 & 127;
                    int b = row >> 10, s = row & 1023;
                    half_t* dst = (which == 0) ? Qp : ((which == 1) ? Kp : Vp);
                    dst[(((long)(b * 4 + h) * 1024 + s) << 7) + d] = (half_t)v;
                } else if constexpr (EPI == EPI_S) {
                    Cf[(long)z * sC + (long)row * N + col] = v * scale;
                } else if constexpr (EPI == EPI_PV) {
                    int bh = zoff + z;
                    int b = bh >> 2, h = bh & 3;
                    Cf[((long)(b * 1024 + row) * 512) + h * 128 + col] = v;
                }
            }
        }
    }
}

// ---------------- split-K reduction: out = [relu](sum_z P_z), in-place-safe ----------------
template<int KS, bool RELU>
__global__ void reduce_kernel(const float* __restrict__ P, float* __restrict__ out, long MN) {
    long i = ((long)blockIdx.x * 256 + threadIdx.x) * 4;
    if (i >= MN) return;
    f32x4 s = *(const f32x4*)&P[i];
    #pragma unroll
    for (int zz = 1; zz < KS; ++zz) {
        f32x4 t = *(const f32x4*)&P[(size_t)zz * MN + i];
        s += t;
    }
    if constexpr (RELU) {
        s[0] = fmaxf(s[0], 0.f); s[1] = fmaxf(s[1], 0.f);
        s[2] = fmaxf(s[2], 0.f); s[3] = fmaxf(s[3], 0.f);
    }
    *(f32x4*)&out[i] = s;
}

// ---------------- V transpose: [bh][s][d] -> [bh][d][s] (bit-pattern copy) ----------------
__global__ void transpose_v(const ushort_t* __restrict__ V, ushort_t* __restrict__ Vt) {
    __shared__ ushort_t t[64][72];
    int s0 = blockIdx.x * 64, d0 = blockIdx.y * 64, bh = blockIdx.z;
    const ushort_t* Vb = V + (long)bh * 1024 * 128;
    ushort_t* Vtb = Vt + (long)bh * 128 * 1024;
    int tid = threadIdx.x;
    int r = tid >> 2, g = tid & 3;
    #pragma unroll
    for (int j = 0; j < 16; ++j)
        t[r][g * 16 + j] = Vb[(long)(s0 + r) * 128 + d0 + g * 16 + j];
    __syncthreads();
    #pragma unroll
    for (int j = 0; j < 16; ++j)
        Vtb[(long)(d0 + r) * 1024 + s0 + g * 16 + j] = t[g * 16 + j][r];
}

// ---------------- softmax over rows of 1024, fp32 in -> fp16 out ----------------
__global__ void softmax_kernel(const float* __restrict__ S, half_t* __restrict__ P) {
    long row = (long)blockIdx.x * 4 + (threadIdx.x >> 6);
    int lane = threadIdx.x & 63;
    const float* Sr = S + row * 1024;
    f32x4 v[4];
    float mx = -3.0e38f;
    #pragma unroll
    for (int c = 0; c < 4; ++c) {
        v[c] = *(const f32x4*)&Sr[c * 256 + lane * 4];
        mx = fmaxf(mx, fmaxf(fmaxf(v[c][0], v[c][1]), fmaxf(v[c][2], v[c][3])));
    }
    #pragma unroll
    for (int off = 32; off > 0; off >>= 1) mx = fmaxf(mx, __shfl_xor(mx, off));
    float sum = 0.0f;
    #pragma unroll
    for (int c = 0; c < 4; ++c) {
        v[c][0] = __expf(v[c][0] - mx); v[c][1] = __expf(v[c][1] - mx);
        v[c][2] = __expf(v[c][2] - mx); v[c][3] = __expf(v[c][3] - mx);
        sum += v[c][0] + v[c][1] + v[c][2] + v[c][3];
    }
    #pragma unroll
    for (int off = 32; off > 0; off >>= 1) sum += __shfl_xor(sum, off);
    float inv = 1.0f / sum;
    half_t* Pr = P + row * 1024;
    #pragma unroll
    for (int c = 0; c < 4; ++c) {
        half4 o = { (half_t)(v[c][0] * inv), (half_t)(v[c][1] * inv),
                    (half_t)(v[c][2] * inv), (half_t)(v[c][3] * inv) };
        *(half4*)&Pr[c * 256 + lane * 4] = o;
    }
}

// ---------------- residual + LayerNorm over rows of 512 ----------------
__global__ void ln_kernel(const float* __restrict__ O, const float* __restrict__ X,
                          const float* __restrict__ g, const float* __restrict__ b,
                          float* __restrict__ out) {
    long row = (long)blockIdx.x * 4 + (threadIdx.x >> 6);
    int lane = threadIdx.x & 63;
    long base = row * 512 + lane * 8;
    f32x4 o0 = *(const f32x4*)&O[base], o1 = *(const f32x4*)&O[base + 4];
    f32x4 x0 = *(const f32x4*)&X[base], x1 = *(const f32x4*)&X[base + 4];
    float y[8];
    #pragma unroll
    for (int j = 0; j < 4; ++j) { y[j] = o0[j] + x0[j]; y[j + 4] = o1[j] + x1[j]; }
    float s = 0.f;
    #pragma unroll
    for (int j = 0; j < 8; ++j) s += y[j];
    #pragma unroll
    for (int off = 32; off > 0; off >>= 1) s += __shfl_xor(s, off);
    float mu = s * (1.0f / 512.0f);
    float vs = 0.f;
    #pragma unroll
    for (int j = 0; j < 8; ++j) { float d = y[j] - mu; vs += d * d; }
    #pragma unroll
    for (int off = 32; off > 0; off >>= 1) vs += __shfl_xor(vs, off);
    float r = rsqrtf(vs * (1.0f / 512.0f) + 1e-5f);
    f32x4 w0 = *(const f32x4*)&g[lane * 8], w1 = *(const f32x4*)&g[lane * 8 + 4];
    f32x4 b0 = *(const f32x4*)&b[lane * 8], b1 = *(const f32x4*)&b[lane * 8 + 4];
    f32x4 r0, r1;
    #pragma unroll
    for (int j = 0; j < 4; ++j) {
        r0[j] = (y[j] - mu) * r * w0[j] + b0[j];
        r1[j] = (y[j + 4] - mu) * r * w1[j] + b1[j];
    }
    *(f32x4*)&out[base] = r0;
    *(f32x4*)&out[base + 4] = r1;
}

// ---------------- launch ----------------
extern "C" void kernel_launch(void* const* d_in, const int* in_sizes, int n_in,
                              void* d_out, int out_size, void* d_ws, size_t ws_size,
                              hipStream_t stream) {
    const float* x         = (const float*)d_in[0];
    const float* k1_base   = (const float*)d_in[1];
    const float* k1_spline = (const float*)d_in[2];
    const float* k2_base   = (const float*)d_in[3];
    const float* k2_spline = (const float*)d_in[4];
    const float* q_base    = (const float*)d_in[5];
    const float* q_spline  = (const float*)d_in[6];
    const float* k_base    = (const float*)d_in[7];
    const float* k_spline  = (const float*)d_in[8];
    const float* v_base    = (const float*)d_in[9];
    const float* v_spline  = (const float*)d_in[10];
    const float* o_base    = (const float*)d_in[11];
    const float* o_spline  = (const float*)d_in[12];
    const float* ln_w      = (const float*)d_in[13];
    const float* ln_b      = (const float*)d_in[14];
    float* out = (float*)d_out;

    constexpr int Dm = 512, HD = 1024, NR = 8192;
    constexpr int K1 = 9 * Dm;   // 4608
    constexpr int K2 = 9 * HD;   // 9216
    constexpr long SQ = (long)1024 * 128;       // per-bh Q/K/V stride (elements)
    constexpr long SS = (long)1024 * 1024;      // per-bh score stride (elements)
    constexpr size_t MB = 1024 * 1024;

    // ---- workspace: weights (72 MB) + arena (152 MB used) = 224 MB peak (proven-safe < 236) ----
    char* p = (char*)d_ws;
    size_t off = 0;
    auto take = [&](size_t bytes) -> char* {
        char* r = p + off;
        off += (bytes + 255) & ~(size_t)255;
        return r;
    };
    half_t* W1hi = (half_t*)take((size_t)HD * K1 * 2);        //  9 MB
    half_t* W2hi = (half_t*)take((size_t)Dm * K2 * 2);        //  9 MB
    half_t* Wqhi = (half_t*)take((size_t)3 * Dm * K1 * 2);    // 13.5 MB
    half_t* Wohi = (half_t*)take((size_t)Dm * K1 * 2);        //  4.5 MB
    half_t* W1lo = (half_t*)take((size_t)HD * K1 * 2);
    half_t* W2lo = (half_t*)take((size_t)Dm * K2 * 2);
    half_t* Wqlo = (half_t*)take((size_t)3 * Dm * K1 * 2);
    half_t* Wolo = (half_t*)take((size_t)Dm * K1 * 2);
    char*   A    = take((size_t)152 * MB);                    // arena
    (void)ws_size; (void)in_sizes; (void)n_in; (void)out_size;

    // arena phase map (offsets in MB):
    // A: E1 @0..72 | P1 @72..136 (2x32) | H1 = alias P1 slice0 @72..104
    // B: E2c @0..72 | H1 @72..104 | P2 @104..136 (4x8) | H2 @136..152
    // C: E3 @0..72 | Q @72..80 K @80..88 V @88..96 | H2 @136..152
    // D: Schk @0..32 | Pchk @32..48 | Vt @96..104 | AO @104..120
    // E: E4 @0..72 | AO @104..120 | P3 @120..152 (2x16) | Ofp = alias P3 slice0 @120..136
    half_t* E1   = (half_t*)(A);
    float*  P1   = (float*)(A + 72 * MB);
    float*  H1   = P1;                           // in-place reduce target
    half_t* E2   = (half_t*)(A);
    float*  P2   = (float*)(A + 104 * MB);
    float*  H2   = (float*)(A + 136 * MB);
    half_t* E3   = (half_t*)(A);
    half_t* Qb   = (half_t*)(A + 72 * MB);
    half_t* Kb   = (half_t*)(A + 80 * MB);
    half_t* Vb   = (half_t*)(A + 88 * MB);
    float*  Schk = (float*)(A);
    half_t* Pchk = (half_t*)(A + 32 * MB);
    half_t* Vt   = (half_t*)(A + 96 * MB);
    float*  AO   = (float*)(A + 104 * MB);
    half_t* E4   = (half_t*)(A);
    float*  P3   = (float*)(A + 120 * MB);
    float*  Ofp  = P3;                           // in-place reduce target

    // pack weights to fp16 hi/lo [out][9][in]
    pack_kernel<Dm><<<(HD * Dm) / 256, 256, 0, stream>>>(k1_base, k1_spline, W1hi, W1lo, HD);
    pack_kernel<HD><<<(Dm * HD) / 256, 256, 0, stream>>>(k2_base, k2_spline, W2hi, W2lo, Dm);
    pack_kernel<Dm><<<(Dm * Dm) / 256, 256, 0, stream>>>(q_base, q_spline, Wqhi, Wqlo, Dm);
    pack_kernel<Dm><<<(Dm * Dm) / 256, 256, 0, stream>>>(k_base, k_spline, Wqhi + (size_t)Dm * K1, Wqlo + (size_t)Dm * K1, Dm);
    pack_kernel<Dm><<<(Dm * Dm) / 256, 256, 0, stream>>>(v_base, v_spline, Wqhi + (size_t)2 * Dm * K1, Wqlo + (size_t)2 * Dm * K1, Dm);
    pack_kernel<Dm><<<(Dm * Dm) / 256, 256, 0, stream>>>(o_base, o_spline, Wohi, Wolo, Dm);

    // KAN1: E1 = expand(x); P1 = split-K(E1 @ W1^T); H1 = relu(P1_0 + P1_1)  [1024 blocks]
    expand_kernel<Dm><<<(NR * Dm) / 256, 256, 0, stream>>>(x, E1, NR);
    gemm_t<EPI_PART, 128, 2, 2><<<dim3(NR / 128, HD / 128, 2), 256, 0, stream>>>(
        (const ushort_t*)E1, (const ushort_t*)W1hi, (const ushort_t*)W1lo,
        nullptr, P1, nullptr, nullptr, nullptr, NR, HD, K1, 0, 0, 0, 1.f, 0);
    reduce_kernel<2, true><<<(NR * HD) / 1024, 256, 0, stream>>>(P1, H1, (long)NR * HD);

    // KAN2 (2 M-chunks): P2 = split-K4(E2c @ W2^T); H2c = sum  [1024 blocks/chunk]
    for (int c = 0; c < 2; ++c) {
        expand_kernel<HD><<<(4096 * HD) / 256, 256, 0, stream>>>(H1 + (size_t)c * 4096 * HD, E2, 4096);
        gemm_t<EPI_PART, 64, 2, 4><<<dim3(4096 / 128, Dm / 64, 4), 256, 0, stream>>>(
            (const ushort_t*)E2, (const ushort_t*)W2hi, (const ushort_t*)W2lo,
            nullptr, P2, nullptr, nullptr, nullptr, 4096, Dm, K2, 0, 0, 0, 1.f, 0);
        reduce_kernel<4, false><<<(4096 * Dm) / 1024, 256, 0, stream>>>(P2, H2 + (size_t)c * 4096 * Dm, (long)4096 * Dm);
    }

    // QKV projections (fused, direct epilogue): E3 = expand(H2) -> Q/K/V [b,h,s,d] fp16  [1536 blocks]
    expand_kernel<Dm><<<(NR * Dm) / 256, 256, 0, stream>>>(H2, E3, NR);
    gemm_t<EPI_QKV, 64, 2, 1><<<dim3(NR / 128, (3 * Dm) / 64, 1), 256, 0, stream>>>(
        (const ushort_t*)E3, (const ushort_t*)Wqhi, (const ushort_t*)Wqlo,
        nullptr, nullptr, Qb, Kb, Vb, NR, 3 * Dm, K1, 0, 0, 0, 1.f, 0);

    // attention, 4 chunks of 8 bh: S = (Q K^T)/sqrt(128); P = softmax(S); AO = P V (fp32)
    transpose_v<<<dim3(16, 2, 32), 256, 0, stream>>>((const ushort_t*)Vb, (ushort_t*)Vt);
    for (int c = 0; c < 4; ++c) {
        int zoff = c * 8;
        gemm_t<EPI_S, 128, 1, 1><<<dim3(8, 8, 8), 256, 0, stream>>>(
            (const ushort_t*)(Qb + (long)zoff * SQ), (const ushort_t*)(Kb + (long)zoff * SQ), nullptr,
            Schk, nullptr, nullptr, nullptr, nullptr,
            1024, 1024, 128, SQ, SQ, SS, 0.08838834764831845f, 0);
        softmax_kernel<<<(8 * 1024) / 4, 256, 0, stream>>>(Schk, Pchk);
        gemm_t<EPI_PV, 128, 1, 1><<<dim3(8, 1, 8), 256, 0, stream>>>(
            (const ushort_t*)Pchk, (const ushort_t*)(Vt + (long)zoff * SQ), nullptr,
            AO, nullptr, nullptr, nullptr, nullptr,
            1024, 128, 1024, SS, SQ, 0, 1.f, zoff);
    }

    // output projection: E4 = expand(AO); P3 = split-K(E4 @ Wo^T); Ofp = sum  [1024 blocks]
    expand_kernel<Dm><<<(NR * Dm) / 256, 256, 0, stream>>>(AO, E4, NR);
    gemm_t<EPI_PART, 64, 2, 2><<<dim3(NR / 128, Dm / 64, 2), 256, 0, stream>>>(
        (const ushort_t*)E4, (const ushort_t*)Wohi, (const ushort_t*)Wolo,
        nullptr, P3, nullptr, nullptr, nullptr, NR, Dm, K1, 0, 0, 0, 1.f, 0);
    reduce_kernel<2, false><<<(NR * Dm) / 1024, 256, 0, stream>>>(P3, Ofp, (long)NR * Dm);

    // residual + LayerNorm
    ln_kernel<<<NR / 4, 256, 0, stream>>>(Ofp, x, ln_w, ln_b, out);
}

// Round 6
// 997.764 us; speedup vs baseline: 1.6159x; 1.1993x over previous
//
#include <hip/hip_runtime.h>
#include <cstdint>

typedef unsigned short ushort_t;
typedef _Float16 half_t;
typedef __attribute__((ext_vector_type(8))) short short8;
typedef __attribute__((ext_vector_type(8))) half_t half8;
typedef __attribute__((ext_vector_type(4))) half_t half4;
typedef __attribute__((ext_vector_type(4))) float f32x4;

// ---------------- helpers ----------------
__device__ __forceinline__ void gld_lds16(const ushort_t* g, ushort_t* l) {
    __builtin_amdgcn_global_load_lds((const __attribute__((address_space(1))) void*)g,
                                     (__attribute__((address_space(3))) void*)l,
                                     16, 0, 0);
}

// ---------------- expand: X fp32 [N][IN] -> E fp16 [N][9][IN] ----------------
// plane c=0 is silu(x); planes c=1..8 are the 8 cubic B-spline bases (uniform grid).
template<int IN>
__global__ void expand_kernel(const float* __restrict__ X, half_t* __restrict__ E, int nrows) {
    int idx = blockIdx.x * 256 + threadIdx.x;
    if (idx >= nrows * IN) return;
    int n = idx / IN, i = idx % IN;
    float x = X[idx];
    float si = x / (1.0f + __expf(-x));
    float u = (x + 2.2f) * 2.5f;
    int ji = (int)floorf(u);
    float f = u - (float)ji;
    if (!(ji >= 0 && ji <= 10)) ji = -100;      // outside knot range -> all bases 0
    float f2 = f * f, f3 = f2 * f;
    float w_i   = f3 * (1.0f / 6.0f);                                   // N_{ji}
    float w_im1 = (1.0f + 3.0f * f + 3.0f * f2 - 3.0f * f3) * (1.0f/6.0f);
    float w_im2 = (4.0f - 6.0f * f2 + 3.0f * f3) * (1.0f/6.0f);
    float omf = 1.0f - f;
    float w_im3 = omf * omf * omf * (1.0f / 6.0f);                      // N_{ji-3}
    half_t* Er = E + (long)n * 9 * IN + i;
    Er[0] = (half_t)si;
    #pragma unroll
    for (int c = 0; c < 8; ++c) {
        float v = 0.0f;
        v = (c == ji    ) ? w_i   : v;
        v = (c == ji - 1) ? w_im1 : v;
        v = (c == ji - 2) ? w_im2 : v;
        v = (c == ji - 3) ? w_im3 : v;
        Er[(long)(c + 1) * IN] = (half_t)v;
    }
}

// ---------------- pack weights hi/lo: base[o][i], spline[o][i][8] -> Whi/Wlo fp16 [o][9][IN] ----------------
template<int IN>
__global__ void pack_kernel(const float* __restrict__ base, const float* __restrict__ spline,
                            half_t* __restrict__ Whi, half_t* __restrict__ Wlo, int nout) {
    int idx = blockIdx.x * 256 + threadIdx.x;
    if (idx >= nout * IN) return;
    int o = idx / IN, i = idx % IN;
    long r0 = (long)o * 9 * IN + i;
    float w[9];
    w[0] = base[idx];
    const f32x4* sp = (const f32x4*)(spline + (long)idx * 8);
    f32x4 s0 = sp[0], s1 = sp[1];
    w[1] = s0[0]; w[2] = s0[1]; w[3] = s0[2]; w[4] = s0[3];
    w[5] = s1[0]; w[6] = s1[1]; w[7] = s1[2]; w[8] = s1[3];
    #pragma unroll
    for (int c = 0; c < 9; ++c) {
        half_t hi = (half_t)w[c];
        half_t lo = (half_t)(w[c] - (float)hi);
        Whi[r0 + (long)c * IN] = hi;
        Wlo[r0 + (long)c * IN] = lo;
    }
}

// ---------------- GEMM: C[M][N] = A[M][K] @ B[N][K]^T, fp16 in / fp32 acc ----------------
// tile 128 x TN, BK=64, 4 waves (2x2). KSPLIT==1: serial hi(+lo) passes, direct epilogue,
// blockIdx.z = batch. KSPLIT>1: blockIdx.z = K-split slice over virtual 2K (hi then lo),
// writes fp32 partial P[z*M*N + row*N + col]; epilogue applied by reduce_kernel.
enum { EPI_PART = 0, EPI_QKV = 1, EPI_S = 2, EPI_PV = 3 };

template<int EPI, int TN, int NPASS, int KSPLIT>
__global__ void gemm_t(const ushort_t* __restrict__ A, const ushort_t* __restrict__ Bhi,
                       const ushort_t* __restrict__ Blo, float* __restrict__ Cf,
                       float* __restrict__ P,
                       half_t* __restrict__ Qp, half_t* __restrict__ Kp, half_t* __restrict__ Vp,
                       int M, int N, int K, long sA, long sB, long sC, float scale, int zoff) {
    constexpr int NF = TN / 32;                 // B-frags per wave (2 or 4)
    __shared__ ushort_t As[128 * 64];
    __shared__ ushort_t Bs[TN * 64];
    const int tid = threadIdx.x;
    const int lane = tid & 63;
    const int wave = tid >> 6;
    const int wm = wave >> 1, wn = wave & 1;
    const int bm = blockIdx.x * 128, bn = blockIdx.y * TN;
    const int z = blockIdx.z;
    const int l15 = lane & 15, l16 = lane >> 4;

    f32x4 acc[4][NF];
    #pragma unroll
    for (int m = 0; m < 4; ++m)
        #pragma unroll
        for (int n = 0; n < NF; ++n) acc[m][n] = (f32x4){0.f, 0.f, 0.f, 0.f};

    auto sweep = [&](const ushort_t* Ab, const ushort_t* Bb, int ka, int kb) {
        for (int kt = ka; kt < kb; kt += 64) {
            #pragma unroll
            for (int r = 0; r < 4; ++r) {
                int chunk = r * 256 + tid;      // A: 128x64 fp16 = 1024 chunks of 8
                gld_lds16(Ab + (long)(bm + (chunk >> 3)) * K + kt + ((chunk & 7) << 3), &As[chunk * 8]);
            }
            #pragma unroll
            for (int r = 0; r < NF; ++r) {
                int chunk = r * 256 + tid;      // B: TNx64
                gld_lds16(Bb + (long)(bn + (chunk >> 3)) * K + kt + ((chunk & 7) << 3), &Bs[chunk * 8]);
            }
            __syncthreads();
            #pragma unroll
            for (int kk = 0; kk < 2; ++kk) {
                half8 af[4], bfr[NF];
                #pragma unroll
                for (int m = 0; m < 4; ++m)
                    af[m] = __builtin_bit_cast(half8, *(const short8*)&As[(wm * 64 + m * 16 + l15) * 64 + kk * 32 + l16 * 8]);
                #pragma unroll
                for (int n = 0; n < NF; ++n)
                    bfr[n] = __builtin_bit_cast(half8, *(const short8*)&Bs[(wn * (TN / 2) + n * 16 + l15) * 64 + kk * 32 + l16 * 8]);
                #pragma unroll
                for (int m = 0; m < 4; ++m)
                    #pragma unroll
                    for (int n = 0; n < NF; ++n)
                        acc[m][n] = __builtin_amdgcn_mfma_f32_16x16x32_f16(af[m], bfr[n], acc[m][n], 0, 0, 0);
            }
            __syncthreads();
        }
    };

    if constexpr (KSPLIT > 1) {
        constexpr int half = KSPLIT / 2;
        const ushort_t* Bsel = (z >= half) ? Blo : Bhi;
        int kc = K / half;
        int ka = (z % half) * kc;
        sweep(A, Bsel, ka, ka + kc);
    } else {
        const ushort_t* Ab = A + (long)z * sA;
        sweep(Ab, Bhi + (long)z * sB, 0, K);
        if constexpr (NPASS == 2) sweep(Ab, Blo + (long)z * sB, 0, K);
    }

    // epilogue: C/D layout col=lane&15, row=(lane>>4)*4+j (m89-verified)
    #pragma unroll
    for (int m = 0; m < 4; ++m) {
        #pragma unroll
        for (int n = 0; n < NF; ++n) {
            #pragma unroll
            for (int j = 0; j < 4; ++j) {
                int row = bm + wm * 64 + m * 16 + l16 * 4 + j;
                int col = bn + wn * (TN / 2) + n * 16 + l15;
                float v = acc[m][n][j];
                if constexpr (KSPLIT > 1) {
                    P[(size_t)z * M * N + (long)row * N + col] = v;
                } else if constexpr (EPI == EPI_QKV) {
                    // col in [0,1536): 0..511 Q, 512..1023 K, 1024..1535 V; layout [b,h,s,d]
                    int which = col >> 9, w5 = col & 511, h = w5 >> 7, d = w5 & 127;
                    int b = row >> 10, s = row & 1023;
                    half_t* dst = (which == 0) ? Qp : ((which == 1) ? Kp : Vp);
                    dst[(((long)(b * 4 + h) * 1024 + s) << 7) + d] = (half_t)v;
                } else if constexpr (EPI == EPI_S) {
                    Cf[(long)z * sC + (long)row * N + col] = v * scale;
                } else if constexpr (EPI == EPI_PV) {
                    int bh = zoff + z;
                    int b = bh >> 2, h = bh & 3;
                    Cf[((long)(b * 1024 + row) * 512) + h * 128 + col] = v;
                }
            }
        }
    }
}

// ---------------- split-K reduction: out = [relu](sum_z P_z), in-place-safe ----------------
template<int KS, bool RELU>
__global__ void reduce_kernel(const float* __restrict__ P, float* __restrict__ out, long MN) {
    long i = ((long)blockIdx.x * 256 + threadIdx.x) * 4;
    if (i >= MN) return;
    f32x4 s = *(const f32x4*)&P[i];
    #pragma unroll
    for (int zz = 1; zz < KS; ++zz) {
        f32x4 t = *(const f32x4*)&P[(size_t)zz * MN + i];
        s += t;
    }
    if constexpr (RELU) {
        s[0] = fmaxf(s[0], 0.f); s[1] = fmaxf(s[1], 0.f);
        s[2] = fmaxf(s[2], 0.f); s[3] = fmaxf(s[3], 0.f);
    }
    *(f32x4*)&out[i] = s;
}

// ---------------- V transpose: [bh][s][d] -> [bh][d][s] (bit-pattern copy) ----------------
__global__ void transpose_v(const ushort_t* __restrict__ V, ushort_t* __restrict__ Vt) {
    __shared__ ushort_t t[64][72];
    int s0 = blockIdx.x * 64, d0 = blockIdx.y * 64, bh = blockIdx.z;
    const ushort_t* Vb = V + (long)bh * 1024 * 128;
    ushort_t* Vtb = Vt + (long)bh * 128 * 1024;
    int tid = threadIdx.x;
    int r = tid >> 2, g = tid & 3;
    #pragma unroll
    for (int j = 0; j < 16; ++j)
        t[r][g * 16 + j] = Vb[(long)(s0 + r) * 128 + d0 + g * 16 + j];
    __syncthreads();
    #pragma unroll
    for (int j = 0; j < 16; ++j)
        Vtb[(long)(d0 + r) * 1024 + s0 + g * 16 + j] = t[g * 16 + j][r];
}

// ---------------- softmax over rows of 1024, fp32 in -> fp16 out ----------------
__global__ void softmax_kernel(const float* __restrict__ S, half_t* __restrict__ P) {
    long row = (long)blockIdx.x * 4 + (threadIdx.x >> 6);
    int lane = threadIdx.x & 63;
    const float* Sr = S + row * 1024;
    f32x4 v[4];
    float mx = -3.0e38f;
    #pragma unroll
    for (int c = 0; c < 4; ++c) {
        v[c] = *(const f32x4*)&Sr[c * 256 + lane * 4];
        mx = fmaxf(mx, fmaxf(fmaxf(v[c][0], v[c][1]), fmaxf(v[c][2], v[c][3])));
    }
    #pragma unroll
    for (int off = 32; off > 0; off >>= 1) mx = fmaxf(mx, __shfl_xor(mx, off));
    float sum = 0.0f;
    #pragma unroll
    for (int c = 0; c < 4; ++c) {
        v[c][0] = __expf(v[c][0] - mx); v[c][1] = __expf(v[c][1] - mx);
        v[c][2] = __expf(v[c][2] - mx); v[c][3] = __expf(v[c][3] - mx);
        sum += v[c][0] + v[c][1] + v[c][2] + v[c][3];
    }
    #pragma unroll
    for (int off = 32; off > 0; off >>= 1) sum += __shfl_xor(sum, off);
    float inv = 1.0f / sum;
    half_t* Pr = P + row * 1024;
    #pragma unroll
    for (int c = 0; c < 4; ++c) {
        half4 o = { (half_t)(v[c][0] * inv), (half_t)(v[c][1] * inv),
                    (half_t)(v[c][2] * inv), (half_t)(v[c][3] * inv) };
        *(half4*)&Pr[c * 256 + lane * 4] = o;
    }
}

// ---------------- residual + LayerNorm over rows of 512 ----------------
__global__ void ln_kernel(const float* __restrict__ O, const float* __restrict__ X,
                          const float* __restrict__ g, const float* __restrict__ b,
                          float* __restrict__ out) {
    long row = (long)blockIdx.x * 4 + (threadIdx.x >> 6);
    int lane = threadIdx.x & 63;
    long base = row * 512 + lane * 8;
    f32x4 o0 = *(const f32x4*)&O[base], o1 = *(const f32x4*)&O[base + 4];
    f32x4 x0 = *(const f32x4*)&X[base], x1 = *(const f32x4*)&X[base + 4];
    float y[8];
    #pragma unroll
    for (int j = 0; j < 4; ++j) { y[j] = o0[j] + x0[j]; y[j + 4] = o1[j] + x1[j]; }
    float s = 0.f;
    #pragma unroll
    for (int j = 0; j < 8; ++j) s += y[j];
    #pragma unroll
    for (int off = 32; off > 0; off >>= 1) s += __shfl_xor(s, off);
    float mu = s * (1.0f / 512.0f);
    float vs = 0.f;
    #pragma unroll
    for (int j = 0; j < 8; ++j) { float d = y[j] - mu; vs += d * d; }
    #pragma unroll
    for (int off = 32; off > 0; off >>= 1) vs += __shfl_xor(vs, off);
    float r = rsqrtf(vs * (1.0f / 512.0f) + 1e-5f);
    f32x4 w0 = *(const f32x4*)&g[lane * 8], w1 = *(const f32x4*)&g[lane * 8 + 4];
    f32x4 b0 = *(const f32x4*)&b[lane * 8], b1 = *(const f32x4*)&b[lane * 8 + 4];
    f32x4 r0, r1;
    #pragma unroll
    for (int j = 0; j < 4; ++j) {
        r0[j] = (y[j] - mu) * r * w0[j] + b0[j];
        r1[j] = (y[j + 4] - mu) * r * w1[j] + b1[j];
    }
    *(f32x4*)&out[base] = r0;
    *(f32x4*)&out[base + 4] = r1;
}

// ---------------- launch ----------------
extern "C" void kernel_launch(void* const* d_in, const int* in_sizes, int n_in,
                              void* d_out, int out_size, void* d_ws, size_t ws_size,
                              hipStream_t stream) {
    const float* x         = (const float*)d_in[0];
    const float* k1_base   = (const float*)d_in[1];
    const float* k1_spline = (const float*)d_in[2];
    const float* k2_base   = (const float*)d_in[3];
    const float* k2_spline = (const float*)d_in[4];
    const float* q_base    = (const float*)d_in[5];
    const float* q_spline  = (const float*)d_in[6];
    const float* k_base    = (const float*)d_in[7];
    const float* k_spline  = (const float*)d_in[8];
    const float* v_base    = (const float*)d_in[9];
    const float* v_spline  = (const float*)d_in[10];
    const float* o_base    = (const float*)d_in[11];
    const float* o_spline  = (const float*)d_in[12];
    const float* ln_w      = (const float*)d_in[13];
    const float* ln_b      = (const float*)d_in[14];
    float* out = (float*)d_out;

    constexpr int Dm = 512, HD = 1024, NR = 8192;
    constexpr int K1 = 9 * Dm;   // 4608
    constexpr int K2 = 9 * HD;   // 9216
    constexpr long SQ = (long)1024 * 128;       // per-bh Q/K/V stride (elements)
    constexpr long SS = (long)1024 * 1024;      // per-bh score stride (elements)
    constexpr size_t MB = 1024 * 1024;

    // ---- workspace: weights (72 MB) + arena (152 MB) = 224 MB peak (proven-safe < 236) ----
    char* p = (char*)d_ws;
    size_t off = 0;
    auto take = [&](size_t bytes) -> char* {
        char* r = p + off;
        off += (bytes + 255) & ~(size_t)255;
        return r;
    };
    half_t* W1hi = (half_t*)take((size_t)HD * K1 * 2);        //  9 MB
    half_t* W2hi = (half_t*)take((size_t)Dm * K2 * 2);        //  9 MB
    half_t* Wqhi = (half_t*)take((size_t)3 * Dm * K1 * 2);    // 13.5 MB
    half_t* Wohi = (half_t*)take((size_t)Dm * K1 * 2);        //  4.5 MB
    half_t* W1lo = (half_t*)take((size_t)HD * K1 * 2);
    half_t* W2lo = (half_t*)take((size_t)Dm * K2 * 2);
    half_t* Wqlo = (half_t*)take((size_t)3 * Dm * K1 * 2);
    half_t* Wolo = (half_t*)take((size_t)Dm * K1 * 2);
    char*   A    = take((size_t)152 * MB);                    // arena
    (void)ws_size; (void)in_sizes; (void)n_in; (void)out_size;

    // arena phase map (offsets in MB):
    // A: E1 @0..72 | P1 @72..136 (2x32) | H1 = alias P1 slice0 @72..104
    // B: E2c @0..72 | H1 @72..104 | P2 @104..136 (4x8) | H2 @136..152
    // C: E3 @0..72 | Q @72..80 K @80..88 V @88..96 | H2 @136..152
    // D: Schk @0..64 (16bh) | Vt @96..104 | AO @104..120 | Pchk @120..152 (16bh)
    // E: E4 @0..72 | AO @104..120 (dead at gemm) | P3 @72..136 (4x16) | Ofp = P3 slice0 @72..88
    half_t* E1   = (half_t*)(A);
    float*  P1   = (float*)(A + 72 * MB);
    float*  H1   = P1;                           // in-place reduce target
    half_t* E2   = (half_t*)(A);
    float*  P2   = (float*)(A + 104 * MB);
    float*  H2   = (float*)(A + 136 * MB);
    half_t* E3   = (half_t*)(A);
    half_t* Qb   = (half_t*)(A + 72 * MB);
    half_t* Kb   = (half_t*)(A + 80 * MB);
    half_t* Vb   = (half_t*)(A + 88 * MB);
    float*  Schk = (float*)(A);
    half_t* Pchk = (half_t*)(A + 120 * MB);
    half_t* Vt   = (half_t*)(A + 96 * MB);
    float*  AO   = (float*)(A + 104 * MB);
    half_t* E4   = (half_t*)(A);
    float*  P3   = (float*)(A + 72 * MB);
    float*  Ofp  = P3;                           // in-place reduce target

    // pack weights to fp16 hi/lo [out][9][in]
    pack_kernel<Dm><<<(HD * Dm) / 256, 256, 0, stream>>>(k1_base, k1_spline, W1hi, W1lo, HD);
    pack_kernel<HD><<<(Dm * HD) / 256, 256, 0, stream>>>(k2_base, k2_spline, W2hi, W2lo, Dm);
    pack_kernel<Dm><<<(Dm * Dm) / 256, 256, 0, stream>>>(q_base, q_spline, Wqhi, Wqlo, Dm);
    pack_kernel<Dm><<<(Dm * Dm) / 256, 256, 0, stream>>>(k_base, k_spline, Wqhi + (size_t)Dm * K1, Wqlo + (size_t)Dm * K1, Dm);
    pack_kernel<Dm><<<(Dm * Dm) / 256, 256, 0, stream>>>(v_base, v_spline, Wqhi + (size_t)2 * Dm * K1, Wqlo + (size_t)2 * Dm * K1, Dm);
    pack_kernel<Dm><<<(Dm * Dm) / 256, 256, 0, stream>>>(o_base, o_spline, Wohi, Wolo, Dm);

    // KAN1: E1 = expand(x); P1 = split-K2(E1 @ W1^T); H1 = relu(P1_0 + P1_1)  [1024 blocks]
    expand_kernel<Dm><<<(NR * Dm) / 256, 256, 0, stream>>>(x, E1, NR);
    gemm_t<EPI_PART, 128, 2, 2><<<dim3(NR / 128, HD / 128, 2), 256, 0, stream>>>(
        (const ushort_t*)E1, (const ushort_t*)W1hi, (const ushort_t*)W1lo,
        nullptr, P1, nullptr, nullptr, nullptr, NR, HD, K1, 0, 0, 0, 1.f, 0);
    reduce_kernel<2, true><<<(NR * HD) / 1024, 256, 0, stream>>>(P1, H1, (long)NR * HD);

    // KAN2 (2 M-chunks): P2 = split-K4(E2c @ W2^T); H2c = sum  [512 blocks/chunk, TN=128]
    for (int c = 0; c < 2; ++c) {
        expand_kernel<HD><<<(4096 * HD) / 256, 256, 0, stream>>>(H1 + (size_t)c * 4096 * HD, E2, 4096);
        gemm_t<EPI_PART, 128, 2, 4><<<dim3(4096 / 128, Dm / 128, 4), 256, 0, stream>>>(
            (const ushort_t*)E2, (const ushort_t*)W2hi, (const ushort_t*)W2lo,
            nullptr, P2, nullptr, nullptr, nullptr, 4096, Dm, K2, 0, 0, 0, 1.f, 0);
        reduce_kernel<4, false><<<(4096 * Dm) / 1024, 256, 0, stream>>>(P2, H2 + (size_t)c * 4096 * Dm, (long)4096 * Dm);
    }

    // QKV projections (fused, direct epilogue): E3 = expand(H2) -> Q/K/V [b,h,s,d] fp16  [768 blocks, TN=128]
    expand_kernel<Dm><<<(NR * Dm) / 256, 256, 0, stream>>>(H2, E3, NR);
    gemm_t<EPI_QKV, 128, 2, 1><<<dim3(NR / 128, (3 * Dm) / 128, 1), 256, 0, stream>>>(
        (const ushort_t*)E3, (const ushort_t*)Wqhi, (const ushort_t*)Wqlo,
        nullptr, nullptr, Qb, Kb, Vb, NR, 3 * Dm, K1, 0, 0, 0, 1.f, 0);

    // attention, 2 chunks of 16 bh: S = (Q K^T)/sqrt(128); P = softmax(S); AO = P V (fp32)
    transpose_v<<<dim3(16, 2, 32), 256, 0, stream>>>((const ushort_t*)Vb, (ushort_t*)Vt);
    for (int c = 0; c < 2; ++c) {
        int zoff = c * 16;
        gemm_t<EPI_S, 128, 1, 1><<<dim3(8, 8, 16), 256, 0, stream>>>(
            (const ushort_t*)(Qb + (long)zoff * SQ), (const ushort_t*)(Kb + (long)zoff * SQ), nullptr,
            Schk, nullptr, nullptr, nullptr, nullptr,
            1024, 1024, 128, SQ, SQ, SS, 0.08838834764831845f, 0);
        softmax_kernel<<<(16 * 1024) / 4, 256, 0, stream>>>(Schk, Pchk);
        gemm_t<EPI_PV, 128, 1, 1><<<dim3(8, 1, 16), 256, 0, stream>>>(
            (const ushort_t*)Pchk, (const ushort_t*)(Vt + (long)zoff * SQ), nullptr,
            AO, nullptr, nullptr, nullptr, nullptr,
            1024, 128, 1024, SS, SQ, 0, 1.f, zoff);
    }

    // output projection: E4 = expand(AO); P3 = split-K4(E4 @ Wo^T); Ofp = sum  [1024 blocks, TN=128]
    expand_kernel<Dm><<<(NR * Dm) / 256, 256, 0, stream>>>(AO, E4, NR);
    gemm_t<EPI_PART, 128, 2, 4><<<dim3(NR / 128, Dm / 128, 4), 256, 0, stream>>>(
        (const ushort_t*)E4, (const ushort_t*)Wohi, (const ushort_t*)Wolo,
        nullptr, P3, nullptr, nullptr, nullptr, NR, Dm, K1, 0, 0, 0, 1.f, 0);
    reduce_kernel<4, false><<<(NR * Dm) / 1024, 256, 0, stream>>>(P3, Ofp, (long)NR * Dm);

    // residual + LayerNorm
    ln_kernel<<<NR / 4, 256, 0, stream>>>(Ofp, x, ln_w, ln_b, out);
}

// Round 7
// 889.511 us; speedup vs baseline: 1.8126x; 1.1217x over previous
//
#include <hip/hip_runtime.h>
#include <cstdint>

typedef unsigned short ushort_t;
typedef _Float16 half_t;
typedef __attribute__((ext_vector_type(8))) short short8;
typedef __attribute__((ext_vector_type(8))) half_t half8;
typedef __attribute__((ext_vector_type(4))) half_t half4;
typedef __attribute__((ext_vector_type(4))) float f32x4;

// ---------------- helpers ----------------
__device__ __forceinline__ void gld_lds16(const ushort_t* g, ushort_t* l) {
    __builtin_amdgcn_global_load_lds((const __attribute__((address_space(1))) void*)g,
                                     (__attribute__((address_space(3))) void*)l,
                                     16, 0, 0);
}

// ---------------- expand: X fp32 [N][IN] -> E fp16 [N][9][IN] ----------------
template<int IN>
__global__ void expand_kernel(const float* __restrict__ X, half_t* __restrict__ E, int nrows) {
    int idx = blockIdx.x * 256 + threadIdx.x;
    if (idx >= nrows * IN) return;
    int n = idx / IN, i = idx % IN;
    float x = X[idx];
    float si = x / (1.0f + __expf(-x));
    float u = (x + 2.2f) * 2.5f;
    int ji = (int)floorf(u);
    float f = u - (float)ji;
    if (!(ji >= 0 && ji <= 10)) ji = -100;      // outside knot range -> all bases 0
    float f2 = f * f, f3 = f2 * f;
    float w_i   = f3 * (1.0f / 6.0f);
    float w_im1 = (1.0f + 3.0f * f + 3.0f * f2 - 3.0f * f3) * (1.0f/6.0f);
    float w_im2 = (4.0f - 6.0f * f2 + 3.0f * f3) * (1.0f/6.0f);
    float omf = 1.0f - f;
    float w_im3 = omf * omf * omf * (1.0f / 6.0f);
    half_t* Er = E + (long)n * 9 * IN + i;
    Er[0] = (half_t)si;
    #pragma unroll
    for (int c = 0; c < 8; ++c) {
        float v = 0.0f;
        v = (c == ji    ) ? w_i   : v;
        v = (c == ji - 1) ? w_im1 : v;
        v = (c == ji - 2) ? w_im2 : v;
        v = (c == ji - 3) ? w_im3 : v;
        Er[(long)(c + 1) * IN] = (half_t)v;
    }
}

// ---------------- pack weights hi/lo ----------------
template<int IN>
__global__ void pack_kernel(const float* __restrict__ base, const float* __restrict__ spline,
                            half_t* __restrict__ Whi, half_t* __restrict__ Wlo, int nout) {
    int idx = blockIdx.x * 256 + threadIdx.x;
    if (idx >= nout * IN) return;
    int o = idx / IN, i = idx % IN;
    long r0 = (long)o * 9 * IN + i;
    float w[9];
    w[0] = base[idx];
    const f32x4* sp = (const f32x4*)(spline + (long)idx * 8);
    f32x4 s0 = sp[0], s1 = sp[1];
    w[1] = s0[0]; w[2] = s0[1]; w[3] = s0[2]; w[4] = s0[3];
    w[5] = s1[0]; w[6] = s1[1]; w[7] = s1[2]; w[8] = s1[3];
    #pragma unroll
    for (int c = 0; c < 9; ++c) {
        half_t hi = (half_t)w[c];
        half_t lo = (half_t)(w[c] - (float)hi);
        Whi[r0 + (long)c * IN] = hi;
        Wlo[r0 + (long)c * IN] = lo;
    }
}

enum { EPI_PART = 0, EPI_QKV = 1, EPI_S = 2, EPI_PV = 3, EPI_RELU = 4 };

// ---------------- pipelined GEMM: 256x128 tile, 3-slot LDS, counted vmcnt ----------------
// C[M][N] = A[M][K] @ [Bhi;Blo][N][K]^T over virtual 2*NT K-tiles (hi pass then lo pass).
// KSPLIT>1: blockIdx.z = contiguous slice of virtual tiles -> fp32 partial P[z].
// Swizzle: 16B chunk c of row r lives at LDS chunk (c ^ (r&7)) — applied on global source
// (gld_lds dest stays linear, rule #21) and on ds_read address (same involution).
template<int EPI, int KSPLIT>
__global__ __launch_bounds__(512, 2)
void gemm_p(const ushort_t* __restrict__ A, const ushort_t* __restrict__ Bhi,
            const ushort_t* __restrict__ Blo, float* __restrict__ Cf, float* __restrict__ P,
            half_t* __restrict__ Qp, half_t* __restrict__ Kp, half_t* __restrict__ Vp,
            int M, int N, int K) {
    constexpr int ASLOT = 256 * 64;             // elements per A slot
    constexpr int BSLOT = 128 * 64;
    __shared__ __attribute__((aligned(16))) ushort_t lds[3 * (ASLOT + BSLOT)];  // 144 KB
    const int tid = threadIdx.x;
    const int lane = tid & 63;
    const int wave = tid >> 6;                  // 0..7
    const int wm = wave >> 1, wn = wave & 1;    // 4M x 2N
    const int l15 = lane & 15, l16 = lane >> 4;
    const int bm = blockIdx.x * 256, bn = blockIdx.y * 128;
    const int NT = K >> 6;
    const int kc = (2 * NT) / KSPLIT;           // virtual tiles per slice
    const int t0 = blockIdx.z * kc;

    auto stage = [&](int tt, int s) {
        int pass = (tt >= NT) ? 1 : 0;
        int kt = (tt - (pass ? NT : 0)) << 6;
        const ushort_t* Bb = pass ? Blo : Bhi;
        ushort_t* sA = &lds[s * ASLOT];
        ushort_t* sB = &lds[3 * ASLOT + s * BSLOT];
        #pragma unroll
        for (int r = 0; r < 4; ++r) {           // A: 256x64 = 2048 chunks, 4/thread
            int ch = r * 512 + tid;
            int row = ch >> 3, c = ch & 7;
            gld_lds16(A + (long)(bm + row) * K + kt + ((c ^ (row & 7)) << 3), sA + ch * 8);
        }
        #pragma unroll
        for (int r = 0; r < 2; ++r) {           // B: 128x64 = 1024 chunks, 2/thread
            int ch = r * 512 + tid;
            int row = ch >> 3, c = ch & 7;
            gld_lds16(Bb + (long)(bn + row) * K + kt + ((c ^ (row & 7)) << 3), sB + ch * 8);
        }
    };

    f32x4 acc[4][4];
    #pragma unroll
    for (int m = 0; m < 4; ++m)
        #pragma unroll
        for (int n = 0; n < 4; ++n) acc[m][n] = (f32x4){0.f, 0.f, 0.f, 0.f};

    // prologue: stage tiles t0, t0+1; wait t0 landed (oldest 6 of 12), all waves sync
    stage(t0, 0);
    stage(t0 + 1, 1);
    asm volatile("s_waitcnt vmcnt(6)" ::: "memory");
    __builtin_amdgcn_s_barrier();
    __builtin_amdgcn_sched_barrier(0);

    for (int u = 0; u < kc; ++u) {
        int s = u % 3;
        const ushort_t* sA = &lds[s * ASLOT];
        const ushort_t* sB = &lds[3 * ASLOT + s * BSLOT];
        half8 af[4][2], bf[4][2];
        #pragma unroll
        for (int mf = 0; mf < 4; ++mf)
            #pragma unroll
            for (int kk = 0; kk < 2; ++kk) {
                int row = wm * 64 + mf * 16 + l15;
                int chk = (kk * 4 + l16) ^ (row & 7);
                af[mf][kk] = __builtin_bit_cast(half8, *(const short8*)&sA[row * 64 + chk * 8]);
            }
        #pragma unroll
        for (int nf = 0; nf < 4; ++nf)
            #pragma unroll
            for (int kk = 0; kk < 2; ++kk) {
                int row = wn * 64 + nf * 16 + l15;
                int chk = (kk * 4 + l16) ^ (row & 7);
                bf[nf][kk] = __builtin_bit_cast(half8, *(const short8*)&sB[row * 64 + chk * 8]);
            }
        __builtin_amdgcn_s_setprio(1);
        #pragma unroll
        for (int mf = 0; mf < 4; ++mf)
            #pragma unroll
            for (int nf = 0; nf < 4; ++nf)
                #pragma unroll
                for (int kk = 0; kk < 2; ++kk)
                    acc[mf][nf] = __builtin_amdgcn_mfma_f32_16x16x32_f16(af[mf][kk], bf[nf][kk], acc[mf][nf], 0, 0, 0);
        __builtin_amdgcn_s_setprio(0);
        if (u + 2 < kc) {
            stage(t0 + u + 2, (u + 2) % 3);     // slot (u+2)%3 == (u-1)%3: readers passed last barrier
            asm volatile("s_waitcnt vmcnt(6)" ::: "memory");   // tile u+1 landed, u+2 in flight
        } else {
            asm volatile("s_waitcnt vmcnt(0)" ::: "memory");   // tail drain (last 2 iters only)
        }
        __builtin_amdgcn_s_barrier();
        __builtin_amdgcn_sched_barrier(0);
    }

    // epilogue: C/D layout col=lane&15, row=(lane>>4)*4+j (m89-verified)
    #pragma unroll
    for (int mf = 0; mf < 4; ++mf) {
        #pragma unroll
        for (int nf = 0; nf < 4; ++nf) {
            #pragma unroll
            for (int j = 0; j < 4; ++j) {
                int row = bm + wm * 64 + mf * 16 + l16 * 4 + j;
                int col = bn + wn * 64 + nf * 16 + l15;
                float v = acc[mf][nf][j];
                if constexpr (KSPLIT > 1) {
                    P[(size_t)blockIdx.z * M * N + (long)row * N + col] = v;
                } else if constexpr (EPI == EPI_RELU) {
                    Cf[(long)row * N + col] = fmaxf(v, 0.0f);
                } else if constexpr (EPI == EPI_QKV) {
                    int which = col >> 9, w5 = col & 511, h = w5 >> 7, d = w5 & 127;
                    int b = row >> 10, ss = row & 1023;
                    half_t* dst = (which == 0) ? Qp : ((which == 1) ? Kp : Vp);
                    dst[(((long)(b * 4 + h) * 1024 + ss) << 7) + d] = (half_t)v;
                }
            }
        }
    }
}

// ---------------- legacy 128xTN GEMM (attention only) ----------------
template<int EPI, int TN, int NPASS, int KSPLIT>
__global__ void gemm_t(const ushort_t* __restrict__ A, const ushort_t* __restrict__ Bhi,
                       const ushort_t* __restrict__ Blo, float* __restrict__ Cf,
                       float* __restrict__ P,
                       half_t* __restrict__ Qp, half_t* __restrict__ Kp, half_t* __restrict__ Vp,
                       int M, int N, int K, long sA, long sB, long sC, float scale, int zoff) {
    constexpr int NF = TN / 32;
    __shared__ ushort_t As[128 * 64];
    __shared__ ushort_t Bs[TN * 64];
    const int tid = threadIdx.x;
    const int lane = tid & 63;
    const int wave = tid >> 6;
    const int wm = wave >> 1, wn = wave & 1;
    const int bm = blockIdx.x * 128, bn = blockIdx.y * TN;
    const int z = blockIdx.z;
    const int l15 = lane & 15, l16 = lane >> 4;

    f32x4 acc[4][NF];
    #pragma unroll
    for (int m = 0; m < 4; ++m)
        #pragma unroll
        for (int n = 0; n < NF; ++n) acc[m][n] = (f32x4){0.f, 0.f, 0.f, 0.f};

    auto sweep = [&](const ushort_t* Ab, const ushort_t* Bb, int ka, int kb) {
        for (int kt = ka; kt < kb; kt += 64) {
            #pragma unroll
            for (int r = 0; r < 4; ++r) {
                int chunk = r * 256 + tid;
                gld_lds16(Ab + (long)(bm + (chunk >> 3)) * K + kt + ((chunk & 7) << 3), &As[chunk * 8]);
            }
            #pragma unroll
            for (int r = 0; r < NF; ++r) {
                int chunk = r * 256 + tid;
                gld_lds16(Bb + (long)(bn + (chunk >> 3)) * K + kt + ((chunk & 7) << 3), &Bs[chunk * 8]);
            }
            __syncthreads();
            #pragma unroll
            for (int kk = 0; kk < 2; ++kk) {
                half8 af[4], bfr[NF];
                #pragma unroll
                for (int m = 0; m < 4; ++m)
                    af[m] = __builtin_bit_cast(half8, *(const short8*)&As[(wm * 64 + m * 16 + l15) * 64 + kk * 32 + l16 * 8]);
                #pragma unroll
                for (int n = 0; n < NF; ++n)
                    bfr[n] = __builtin_bit_cast(half8, *(const short8*)&Bs[(wn * (TN / 2) + n * 16 + l15) * 64 + kk * 32 + l16 * 8]);
                #pragma unroll
                for (int m = 0; m < 4; ++m)
                    #pragma unroll
                    for (int n = 0; n < NF; ++n)
                        acc[m][n] = __builtin_amdgcn_mfma_f32_16x16x32_f16(af[m], bfr[n], acc[m][n], 0, 0, 0);
            }
            __syncthreads();
        }
    };

    if constexpr (KSPLIT > 1) {
        constexpr int half = KSPLIT / 2;
        const ushort_t* Bsel = (z >= half) ? Blo : Bhi;
        int kc = K / half;
        int ka = (z % half) * kc;
        sweep(A, Bsel, ka, ka + kc);
    } else {
        const ushort_t* Ab = A + (long)z * sA;
        sweep(Ab, Bhi + (long)z * sB, 0, K);
        if constexpr (NPASS == 2) sweep(Ab, Blo + (long)z * sB, 0, K);
    }

    #pragma unroll
    for (int m = 0; m < 4; ++m) {
        #pragma unroll
        for (int n = 0; n < NF; ++n) {
            #pragma unroll
            for (int j = 0; j < 4; ++j) {
                int row = bm + wm * 64 + m * 16 + l16 * 4 + j;
                int col = bn + wn * (TN / 2) + n * 16 + l15;
                float v = acc[m][n][j];
                if constexpr (KSPLIT > 1) {
                    P[(size_t)z * M * N + (long)row * N + col] = v;
                } else if constexpr (EPI == EPI_S) {
                    Cf[(long)z * sC + (long)row * N + col] = v * scale;
                } else if constexpr (EPI == EPI_PV) {
                    int bh = zoff + z;
                    int b = bh >> 2, h = bh & 3;
                    Cf[((long)(b * 1024 + row) * 512) + h * 128 + col] = v;
                }
            }
        }
    }
}

// ---------------- split-K reduction ----------------
template<int KS, bool RELU>
__global__ void reduce_kernel(const float* __restrict__ P, float* __restrict__ out, long MN) {
    long i = ((long)blockIdx.x * 256 + threadIdx.x) * 4;
    if (i >= MN) return;
    f32x4 s = *(const f32x4*)&P[i];
    #pragma unroll
    for (int zz = 1; zz < KS; ++zz) {
        f32x4 t = *(const f32x4*)&P[(size_t)zz * MN + i];
        s += t;
    }
    if constexpr (RELU) {
        s[0] = fmaxf(s[0], 0.f); s[1] = fmaxf(s[1], 0.f);
        s[2] = fmaxf(s[2], 0.f); s[3] = fmaxf(s[3], 0.f);
    }
    *(f32x4*)&out[i] = s;
}

// ---------------- V transpose ----------------
__global__ void transpose_v(const ushort_t* __restrict__ V, ushort_t* __restrict__ Vt) {
    __shared__ ushort_t t[64][72];
    int s0 = blockIdx.x * 64, d0 = blockIdx.y * 64, bh = blockIdx.z;
    const ushort_t* Vb = V + (long)bh * 1024 * 128;
    ushort_t* Vtb = Vt + (long)bh * 128 * 1024;
    int tid = threadIdx.x;
    int r = tid >> 2, g = tid & 3;
    #pragma unroll
    for (int j = 0; j < 16; ++j)
        t[r][g * 16 + j] = Vb[(long)(s0 + r) * 128 + d0 + g * 16 + j];
    __syncthreads();
    #pragma unroll
    for (int j = 0; j < 16; ++j)
        Vtb[(long)(d0 + r) * 1024 + s0 + g * 16 + j] = t[g * 16 + j][r];
}

// ---------------- softmax ----------------
__global__ void softmax_kernel(const float* __restrict__ S, half_t* __restrict__ P) {
    long row = (long)blockIdx.x * 4 + (threadIdx.x >> 6);
    int lane = threadIdx.x & 63;
    const float* Sr = S + row * 1024;
    f32x4 v[4];
    float mx = -3.0e38f;
    #pragma unroll
    for (int c = 0; c < 4; ++c) {
        v[c] = *(const f32x4*)&Sr[c * 256 + lane * 4];
        mx = fmaxf(mx, fmaxf(fmaxf(v[c][0], v[c][1]), fmaxf(v[c][2], v[c][3])));
    }
    #pragma unroll
    for (int off = 32; off > 0; off >>= 1) mx = fmaxf(mx, __shfl_xor(mx, off));
    float sum = 0.0f;
    #pragma unroll
    for (int c = 0; c < 4; ++c) {
        v[c][0] = __expf(v[c][0] - mx); v[c][1] = __expf(v[c][1] - mx);
        v[c][2] = __expf(v[c][2] - mx); v[c][3] = __expf(v[c][3] - mx);
        sum += v[c][0] + v[c][1] + v[c][2] + v[c][3];
    }
    #pragma unroll
    for (int off = 32; off > 0; off >>= 1) sum += __shfl_xor(sum, off);
    float inv = 1.0f / sum;
    half_t* Pr = P + row * 1024;
    #pragma unroll
    for (int c = 0; c < 4; ++c) {
        half4 o = { (half_t)(v[c][0] * inv), (half_t)(v[c][1] * inv),
                    (half_t)(v[c][2] * inv), (half_t)(v[c][3] * inv) };
        *(half4*)&Pr[c * 256 + lane * 4] = o;
    }
}

// ---------------- residual + LayerNorm ----------------
__global__ void ln_kernel(const float* __restrict__ O, const float* __restrict__ X,
                          const float* __restrict__ g, const float* __restrict__ b,
                          float* __restrict__ out) {
    long row = (long)blockIdx.x * 4 + (threadIdx.x >> 6);
    int lane = threadIdx.x & 63;
    long base = row * 512 + lane * 8;
    f32x4 o0 = *(const f32x4*)&O[base], o1 = *(const f32x4*)&O[base + 4];
    f32x4 x0 = *(const f32x4*)&X[base], x1 = *(const f32x4*)&X[base + 4];
    float y[8];
    #pragma unroll
    for (int j = 0; j < 4; ++j) { y[j] = o0[j] + x0[j]; y[j + 4] = o1[j] + x1[j]; }
    float s = 0.f;
    #pragma unroll
    for (int j = 0; j < 8; ++j) s += y[j];
    #pragma unroll
    for (int off = 32; off > 0; off >>= 1) s += __shfl_xor(s, off);
    float mu = s * (1.0f / 512.0f);
    float vs = 0.f;
    #pragma unroll
    for (int j = 0; j < 8; ++j) { float d = y[j] - mu; vs += d * d; }
    #pragma unroll
    for (int off = 32; off > 0; off >>= 1) vs += __shfl_xor(vs, off);
    float r = rsqrtf(vs * (1.0f / 512.0f) + 1e-5f);
    f32x4 w0 = *(const f32x4*)&g[lane * 8], w1 = *(const f32x4*)&g[lane * 8 + 4];
    f32x4 b0 = *(const f32x4*)&b[lane * 8], b1 = *(const f32x4*)&b[lane * 8 + 4];
    f32x4 r0, r1;
    #pragma unroll
    for (int j = 0; j < 4; ++j) {
        r0[j] = (y[j] - mu) * r * w0[j] + b0[j];
        r1[j] = (y[j + 4] - mu) * r * w1[j] + b1[j];
    }
    *(f32x4*)&out[base] = r0;
    *(f32x4*)&out[base + 4] = r1;
}

// ---------------- launch ----------------
extern "C" void kernel_launch(void* const* d_in, const int* in_sizes, int n_in,
                              void* d_out, int out_size, void* d_ws, size_t ws_size,
                              hipStream_t stream) {
    const float* x         = (const float*)d_in[0];
    const float* k1_base   = (const float*)d_in[1];
    const float* k1_spline = (const float*)d_in[2];
    const float* k2_base   = (const float*)d_in[3];
    const float* k2_spline = (const float*)d_in[4];
    const float* q_base    = (const float*)d_in[5];
    const float* q_spline  = (const float*)d_in[6];
    const float* k_base    = (const float*)d_in[7];
    const float* k_spline  = (const float*)d_in[8];
    const float* v_base    = (const float*)d_in[9];
    const float* v_spline  = (const float*)d_in[10];
    const float* o_base    = (const float*)d_in[11];
    const float* o_spline  = (const float*)d_in[12];
    const float* ln_w      = (const float*)d_in[13];
    const float* ln_b      = (const float*)d_in[14];
    float* out = (float*)d_out;

    constexpr int Dm = 512, HD = 1024, NR = 8192;
    constexpr int K1 = 9 * Dm;   // 4608
    constexpr int K2 = 9 * HD;   // 9216
    constexpr long SQ = (long)1024 * 128;
    constexpr long SS = (long)1024 * 1024;
    constexpr size_t MB = 1024 * 1024;

    char* p = (char*)d_ws;
    size_t off = 0;
    auto take = [&](size_t bytes) -> char* {
        char* r = p + off;
        off += (bytes + 255) & ~(size_t)255;
        return r;
    };
    half_t* W1hi = (half_t*)take((size_t)HD * K1 * 2);
    half_t* W2hi = (half_t*)take((size_t)Dm * K2 * 2);
    half_t* Wqhi = (half_t*)take((size_t)3 * Dm * K1 * 2);
    half_t* Wohi = (half_t*)take((size_t)Dm * K1 * 2);
    half_t* W1lo = (half_t*)take((size_t)HD * K1 * 2);
    half_t* W2lo = (half_t*)take((size_t)Dm * K2 * 2);
    half_t* Wqlo = (half_t*)take((size_t)3 * Dm * K1 * 2);
    half_t* Wolo = (half_t*)take((size_t)Dm * K1 * 2);
    char*   A    = take((size_t)152 * MB);
    (void)ws_size; (void)in_sizes; (void)n_in; (void)out_size;

    // arena phase map (MB):
    // A: E1 @0..72 | H1 @72..104 (direct from gemm_p)
    // B: E2c @0..72 | H1 @72..104 | P2 @104..136 (4x8) | H2 @136..152
    // C: E3 @0..72 | Q @72..80 K @80..88 V @88..96 | H2 @136..152
    // D: Schk @0..64 | Vt @96..104 | AO @104..120 | Pchk @120..152
    // E: E4 @0..72 | P3 @72..104 (2x16) | Ofp = P3 slice0 | AO @104..120
    half_t* E1   = (half_t*)(A);
    float*  H1   = (float*)(A + 72 * MB);
    half_t* E2   = (half_t*)(A);
    float*  P2   = (float*)(A + 104 * MB);
    float*  H2   = (float*)(A + 136 * MB);
    half_t* E3   = (half_t*)(A);
    half_t* Qb   = (half_t*)(A + 72 * MB);
    half_t* Kb   = (half_t*)(A + 80 * MB);
    half_t* Vb   = (half_t*)(A + 88 * MB);
    float*  Schk = (float*)(A);
    half_t* Pchk = (half_t*)(A + 120 * MB);
    half_t* Vt   = (half_t*)(A + 96 * MB);
    float*  AO   = (float*)(A + 104 * MB);
    half_t* E4   = (half_t*)(A);
    float*  P3   = (float*)(A + 72 * MB);
    float*  Ofp  = P3;

    pack_kernel<Dm><<<(HD * Dm) / 256, 256, 0, stream>>>(k1_base, k1_spline, W1hi, W1lo, HD);
    pack_kernel<HD><<<(Dm * HD) / 256, 256, 0, stream>>>(k2_base, k2_spline, W2hi, W2lo, Dm);
    pack_kernel<Dm><<<(Dm * Dm) / 256, 256, 0, stream>>>(q_base, q_spline, Wqhi, Wqlo, Dm);
    pack_kernel<Dm><<<(Dm * Dm) / 256, 256, 0, stream>>>(k_base, k_spline, Wqhi + (size_t)Dm * K1, Wqlo + (size_t)Dm * K1, Dm);
    pack_kernel<Dm><<<(Dm * Dm) / 256, 256, 0, stream>>>(v_base, v_spline, Wqhi + (size_t)2 * Dm * K1, Wqlo + (size_t)2 * Dm * K1, Dm);
    pack_kernel<Dm><<<(Dm * Dm) / 256, 256, 0, stream>>>(o_base, o_spline, Wohi, Wolo, Dm);

    // KAN1: direct ReLU epilogue (no partials)  [256 blocks, 1/CU]
    expand_kernel<Dm><<<(NR * Dm) / 256, 256, 0, stream>>>(x, E1, NR);
    gemm_p<EPI_RELU, 1><<<dim3(NR / 256, HD / 128, 1), 512, 0, stream>>>(
        (const ushort_t*)E1, (const ushort_t*)W1hi, (const ushort_t*)W1lo,
        H1, nullptr, nullptr, nullptr, nullptr, NR, HD, K1);

    // KAN2 (2 M-chunks, KSPLIT=4 over virtual 2K)  [256 blocks/chunk]
    for (int c = 0; c < 2; ++c) {
        expand_kernel<HD><<<(4096 * HD) / 256, 256, 0, stream>>>(H1 + (size_t)c * 4096 * HD, E2, 4096);
        gemm_p<EPI_PART, 4><<<dim3(4096 / 256, Dm / 128, 4), 512, 0, stream>>>(
            (const ushort_t*)E2, (const ushort_t*)W2hi, (const ushort_t*)W2lo,
            nullptr, P2, nullptr, nullptr, nullptr, 4096, Dm, K2);
        reduce_kernel<4, false><<<(4096 * Dm) / 1024, 256, 0, stream>>>(P2, H2 + (size_t)c * 4096 * Dm, (long)4096 * Dm);
    }

    // QKV (direct scatter epilogue)  [384 blocks]
    expand_kernel<Dm><<<(NR * Dm) / 256, 256, 0, stream>>>(H2, E3, NR);
    gemm_p<EPI_QKV, 1><<<dim3(NR / 256, (3 * Dm) / 128, 1), 512, 0, stream>>>(
        (const ushort_t*)E3, (const ushort_t*)Wqhi, (const ushort_t*)Wqlo,
        nullptr, nullptr, Qb, Kb, Vb, NR, 3 * Dm, K1);

    // attention, 2 chunks of 16 bh (legacy kernel)
    transpose_v<<<dim3(16, 2, 32), 256, 0, stream>>>((const ushort_t*)Vb, (ushort_t*)Vt);
    for (int c = 0; c < 2; ++c) {
        int zoff = c * 16;
        gemm_t<EPI_S, 128, 1, 1><<<dim3(8, 8, 16), 256, 0, stream>>>(
            (const ushort_t*)(Qb + (long)zoff * SQ), (const ushort_t*)(Kb + (long)zoff * SQ), nullptr,
            Schk, nullptr, nullptr, nullptr, nullptr,
            1024, 1024, 128, SQ, SQ, SS, 0.08838834764831845f, 0);
        softmax_kernel<<<(16 * 1024) / 4, 256, 0, stream>>>(Schk, Pchk);
        gemm_t<EPI_PV, 128, 1, 1><<<dim3(8, 1, 16), 256, 0, stream>>>(
            (const ushort_t*)Pchk, (const ushort_t*)(Vt + (long)zoff * SQ), nullptr,
            AO, nullptr, nullptr, nullptr, nullptr,
            1024, 128, 1024, SS, SQ, 0, 1.f, zoff);
    }

    // O-proj: KSPLIT=2 (hi | lo)  [256 blocks]
    expand_kernel<Dm><<<(NR * Dm) / 256, 256, 0, stream>>>(AO, E4, NR);
    gemm_p<EPI_PART, 2><<<dim3(NR / 256, Dm / 128, 2), 512, 0, stream>>>(
        (const ushort_t*)E4, (const ushort_t*)Wohi, (const ushort_t*)Wolo,
        nullptr, P3, nullptr, nullptr, nullptr, NR, Dm, K1);
    reduce_kernel<2, false><<<(NR * Dm) / 1024, 256, 0, stream>>>(P3, Ofp, (long)NR * Dm);

    // residual + LayerNorm
    ln_kernel<<<NR / 4, 256, 0, stream>>>(Ofp, x, ln_w, ln_b, out);
}